// Round 1
// baseline (394.765 us; speedup 1.0000x reference)
//
#include <hip/hip_runtime.h>
#include <hip/hip_cooperative_groups.h>

namespace cg = cooperative_groups;

// Problem constants (fixed by reference setup_inputs).
#define N 32
#define T 64
#define C 256
#define L 64
#define TC (T * C)                     // 16384 (t,c) pairs per n
#define BLK_PER_N 64                   // fallback path: blocks along (t,c) per n
#define PAIRS_PER_BLK (TC / BLK_PER_N) // 256

// ---------------------------------------------------------------------------
// Fused cooperative kernel.
// grid = (T/2, N) = (32, 32) blocks x 256 threads. Block (bx, n) owns the two
// full t-rows t = bx and t = bx+32 (each row = C*L floats = 64 KiB of q).
// __launch_bounds__(256, 4) caps VGPR at 128 -> guaranteed 4 blocks/CU ->
// 1024 co-resident blocks exactly; LDS 3.3 KiB/block is far under budget.
// Phase 1: partial[n][bx][l] = sum over this block's (t,c) of q*k (k staged in
// LDS). grid.sync(). Phase 2: every block reduces the 32 partials for its n,
// does softmax in one wave, then out[t,n,c] = dot(q[n,t,c,:], probs).
// ---------------------------------------------------------------------------
__global__ __launch_bounds__(256, 4) void fused_attn_kernel(
    const float* __restrict__ q, const float* __restrict__ k,
    float* __restrict__ partial, float* __restrict__ out) {
  const int n    = blockIdx.y;
  const int bx   = blockIdx.x;            // 0..31
  const int tid  = threadIdx.x;
  const int lane = tid & 63;
  const int wave = tid >> 6;              // 0..3
  const int sub  = lane >> 4;             // quarter-wave in wave
  const int lq   = lane & 15;             // lane within quarter-wave -> l-group
  const int g    = wave * 4 + sub;        // group id 0..15 -> c residue

  __shared__ float sk[2 * C];             // k rows for the two t's (2 KiB)
  __shared__ float sred[4 * L];           // cross-wave reduction (1 KiB)
  __shared__ __align__(16) float probs[L];

  // ---- Phase 1: stage k rows. k[t,n,c] at k[(t*N + n)*C + c]; tid == c. ----
  sk[tid]     = k[(bx * N + n) * C + tid];
  sk[C + tid] = k[((bx + 32) * N + n) * C + tid];
  __syncthreads();

  float4 acc = make_float4(0.f, 0.f, 0.f, 0.f);
  #pragma unroll
  for (int half = 0; half < 2; ++half) {
    const int t = bx + half * 32;
    const float* __restrict__ qrow =
        q + ((size_t)(n * T + t) * C) * L + lq * 4;   // q[n,t,0,4*lq]
    const float* __restrict__ skr = sk + half * C;
    #pragma unroll 4
    for (int c = g; c < C; c += 16) {     // 16 iterations, coalesced float4
      const float4 qv = *reinterpret_cast<const float4*>(qrow + (size_t)c * L);
      const float kv = skr[c];            // LDS broadcast within quarter-wave
      acc.x = fmaf(qv.x, kv, acc.x);
      acc.y = fmaf(qv.y, kv, acc.y);
      acc.z = fmaf(qv.z, kv, acc.z);
      acc.w = fmaf(qv.w, kv, acc.w);
    }
  }
  // Sum the 4 quarter-waves of this wave (same l-groups, different c's).
  acc.x += __shfl_xor(acc.x, 16); acc.y += __shfl_xor(acc.y, 16);
  acc.z += __shfl_xor(acc.z, 16); acc.w += __shfl_xor(acc.w, 16);
  acc.x += __shfl_xor(acc.x, 32); acc.y += __shfl_xor(acc.y, 32);
  acc.z += __shfl_xor(acc.z, 32); acc.w += __shfl_xor(acc.w, 32);

  if (lane < 16) {
    sred[wave * L + lq * 4 + 0] = acc.x;
    sred[wave * L + lq * 4 + 1] = acc.y;
    sred[wave * L + lq * 4 + 2] = acc.z;
    sred[wave * L + lq * 4 + 3] = acc.w;
  }
  __syncthreads();
  if (tid < L) {
    const float s = sred[tid] + sred[L + tid] + sred[2 * L + tid] + sred[3 * L + tid];
    partial[((size_t)n * 32 + bx) * L + tid] = s;   // [n][32][64], 256 KiB total
  }
  __threadfence();
  cg::this_grid().sync();

  // ---- Phase 2a: reduce 32 partials for this n + softmax (one wave). ----
  {
    float s = 0.f;
    const float* __restrict__ pn = partial + (size_t)n * (32 * L);
    #pragma unroll
    for (int b = wave * 8; b < wave * 8 + 8; ++b)
      s += pn[b * L + lane];              // coalesced 256 B per instruction
    sred[wave * L + lane] = s;
  }
  __syncthreads();
  if (tid < L) {
    float v = sred[tid] + sred[L + tid] + sred[2 * L + tid] + sred[3 * L + tid];
    float m = v;
    #pragma unroll
    for (int off = 32; off > 0; off >>= 1) m = fmaxf(m, __shfl_xor(m, off));
    const float e = __expf(v - m);
    float z = e;
    #pragma unroll
    for (int off = 32; off > 0; off >>= 1) z += __shfl_xor(z, off);
    probs[tid] = e / z;
  }
  __syncthreads();

  // ---- Phase 2b: out[t,n,c] = dot(q[n,t,c,:], probs). q re-read is L3-hot. ----
  const float4 pv = *reinterpret_cast<const float4*>(&probs[lq * 4]);
  #pragma unroll
  for (int half = 0; half < 2; ++half) {
    const int t = bx + half * 32;
    const float* __restrict__ qrow =
        q + ((size_t)(n * T + t) * C) * L + lq * 4;
    float* __restrict__ orow = out + (size_t)(t * N + n) * C;
    #pragma unroll 4
    for (int c = g; c < C; c += 16) {
      const float4 qv = *reinterpret_cast<const float4*>(qrow + (size_t)c * L);
      float d = qv.x * pv.x + qv.y * pv.y + qv.z * pv.z + qv.w * pv.w;
      d += __shfl_xor(d, 1);
      d += __shfl_xor(d, 2);
      d += __shfl_xor(d, 4);
      d += __shfl_xor(d, 8);
      if (lq == 0) orow[c] = d;           // 4 lanes/wave write 4 consecutive floats
    }
  }
}

// ---------------------------------------------------------------------------
// Fallback: the previously-verified two-kernel path (used only if the
// cooperative launch is rejected by the runtime).
// ---------------------------------------------------------------------------
__global__ __launch_bounds__(256, 8) void scores_partial_kernel(
    const float* __restrict__ q, const float* __restrict__ k,
    float* __restrict__ partial) {
  const int n    = blockIdx.y;
  const int tid  = threadIdx.x;
  const int lane = tid & 63;
  const int wave = tid >> 6;
  const int sub  = lane >> 4;
  const int lq   = lane & 15;
  const int g    = wave * 4 + sub;

  const int p0 = blockIdx.x * PAIRS_PER_BLK;
  const float* qn = q + (size_t)n * TC * L;

  float4 acc = make_float4(0.f, 0.f, 0.f, 0.f);
  #pragma unroll 4
  for (int i = g; i < PAIRS_PER_BLK; i += 16) {
    const int p = p0 + i;
    const float4 qv = *reinterpret_cast<const float4*>(qn + (size_t)p * L + lq * 4);
    const int t = p >> 8;
    const int c = p & 255;
    const float kv = k[t * (N * C) + n * C + c];
    acc.x = fmaf(qv.x, kv, acc.x);
    acc.y = fmaf(qv.y, kv, acc.y);
    acc.z = fmaf(qv.z, kv, acc.z);
    acc.w = fmaf(qv.w, kv, acc.w);
  }
  acc.x += __shfl_xor(acc.x, 16); acc.y += __shfl_xor(acc.y, 16);
  acc.z += __shfl_xor(acc.z, 16); acc.w += __shfl_xor(acc.w, 16);
  acc.x += __shfl_xor(acc.x, 32); acc.y += __shfl_xor(acc.y, 32);
  acc.z += __shfl_xor(acc.z, 32); acc.w += __shfl_xor(acc.w, 32);

  __shared__ float sdata[4 * L];
  if (lane < 16) {
    sdata[wave * L + lq * 4 + 0] = acc.x;
    sdata[wave * L + lq * 4 + 1] = acc.y;
    sdata[wave * L + lq * 4 + 2] = acc.z;
    sdata[wave * L + lq * 4 + 3] = acc.w;
  }
  __syncthreads();
  if (tid < L) {
    const float s = sdata[tid] + sdata[L + tid] + sdata[2 * L + tid] + sdata[3 * L + tid];
    partial[(size_t)blockIdx.x * (N * L) + n * L + tid] = s;
  }
}

__global__ __launch_bounds__(256, 8) void out_kernel(
    const float* __restrict__ q, const float* __restrict__ partial,
    float* __restrict__ out) {
  const int n    = blockIdx.y;
  const int tid  = threadIdx.x;
  const int lane = tid & 63;
  const int wave = tid >> 6;

  __shared__ float sred[4 * L];
  __shared__ __align__(16) float probs[L];
  {
    float s = 0.f;
    #pragma unroll 4
    for (int b = wave * 16; b < wave * 16 + 16; ++b)
      s += partial[(size_t)b * (N * L) + n * L + lane];
    sred[wave * L + lane] = s;
  }
  __syncthreads();
  if (tid < L) {
    float s = sred[tid] + sred[L + tid] + sred[2 * L + tid] + sred[3 * L + tid];
    float m = s;
    #pragma unroll
    for (int off = 32; off > 0; off >>= 1) m = fmaxf(m, __shfl_xor(m, off));
    const float e = __expf(s - m);
    float sum = e;
    #pragma unroll
    for (int off = 32; off > 0; off >>= 1) sum += __shfl_xor(sum, off);
    probs[tid] = e / sum;
  }
  __syncthreads();

  const int sub = lane >> 4;
  const int lq  = lane & 15;
  const int g   = wave * 4 + sub;

  const float4 pv = *reinterpret_cast<const float4*>(&probs[lq * 4]);
  const int p0 = blockIdx.x * PAIRS_PER_BLK;
  const float* qn = q + (size_t)n * TC * L;

  #pragma unroll 4
  for (int i = g; i < PAIRS_PER_BLK; i += 16) {
    const int p = p0 + i;
    const float4 qv = *reinterpret_cast<const float4*>(qn + (size_t)p * L + lq * 4);
    float d = qv.x * pv.x + qv.y * pv.y + qv.z * pv.z + qv.w * pv.w;
    d += __shfl_xor(d, 1);
    d += __shfl_xor(d, 2);
    d += __shfl_xor(d, 4);
    d += __shfl_xor(d, 8);
    if (lq == 0) {
      const int t = p >> 8;
      const int c = p & 255;
      out[t * (N * C) + n * C + c] = d;
    }
  }
}

extern "C" void kernel_launch(void* const* d_in, const int* in_sizes, int n_in,
                              void* d_out, int out_size, void* d_ws, size_t ws_size,
                              hipStream_t stream) {
  const float* q = (const float*)d_in[0];   // query: (32,64,256,64) fp32
  const float* k = (const float*)d_in[1];   // key:   (64,32,256)    fp32
  float* out = (float*)d_out;               // out:   (64,32,256)    fp32
  float* partial = (float*)d_ws;            // fused: [32][32][64] = 256 KiB

  dim3 grid(T / 2, N);                      // 1024 blocks x 256 threads
  void* args[] = {(void*)&q, (void*)&k, (void*)&partial, (void*)&out};
  hipError_t err = hipLaunchCooperativeKernel(
      (const void*)fused_attn_kernel, grid, dim3(256), args, 0, stream);
  if (err != hipSuccess) {
    // Fallback: proven two-kernel path.
    dim3 g2(BLK_PER_N, N);
    scores_partial_kernel<<<g2, 256, 0, stream>>>(q, k, partial);
    out_kernel<<<g2, 256, 0, stream>>>(q, partial, out);
  }
}

// Round 2
// 213.980 us; speedup vs baseline: 1.8449x; 1.8449x over previous
//
#include <hip/hip_runtime.h>

// Problem constants (fixed by reference setup_inputs).
#define N 32
#define T 64
#define C 256
#define L 64

// ---------------------------------------------------------------------------
// Kernel 1: partial[t][n][l] = sum_c q[n,t,c,l] * k[t,n,c]
// Grid (T, N) = (64,32) blocks x 256 threads = 8 blocks/CU (32 waves/CU).
// Each block owns one full t-row of q (64 KiB, contiguous). k-row (1 KiB)
// staged in LDS once. A quarter-wave (16 lanes) owns one c per iteration;
// lane lq loads float4 q[n,t,c,4lq..4lq+3] (coalesced 16 B/lane, the wave
// covers 1 KiB contiguous) and FMAs against the LDS-broadcast k value.
// ---------------------------------------------------------------------------
__global__ __launch_bounds__(256, 8) void scores_partial_kernel(
    const float* __restrict__ q, const float* __restrict__ k,
    float* __restrict__ partial) {
  const int t    = blockIdx.x;
  const int n    = blockIdx.y;
  const int tid  = threadIdx.x;
  const int lane = tid & 63;
  const int wave = tid >> 6;      // 0..3
  const int sub  = lane >> 4;     // quarter-wave within wave
  const int lq   = lane & 15;     // lane within quarter-wave -> l-group
  const int g    = wave * 4 + sub; // group id 0..15 -> c residue

  __shared__ float sk[C];         // k row for this (t,n): 1 KiB
  __shared__ float sred[4 * L];   // cross-wave reduction: 1 KiB

  sk[tid] = k[(t * N + n) * C + tid];   // tid == c, coalesced
  __syncthreads();

  const float* __restrict__ qrow = q + ((size_t)(n * T + t) * C) * L + lq * 4;

  float4 acc = make_float4(0.f, 0.f, 0.f, 0.f);
  #pragma unroll 4
  for (int c = g; c < C; c += 16) {     // 16 iterations
    const float4 qv = *reinterpret_cast<const float4*>(qrow + (size_t)c * L);
    const float kv = sk[c];             // LDS broadcast within quarter-wave
    acc.x = fmaf(qv.x, kv, acc.x);
    acc.y = fmaf(qv.y, kv, acc.y);
    acc.z = fmaf(qv.z, kv, acc.z);
    acc.w = fmaf(qv.w, kv, acc.w);
  }

  // Sum the 4 quarter-waves of this wave (same l-groups, different c's).
  acc.x += __shfl_xor(acc.x, 16); acc.y += __shfl_xor(acc.y, 16);
  acc.z += __shfl_xor(acc.z, 16); acc.w += __shfl_xor(acc.w, 16);
  acc.x += __shfl_xor(acc.x, 32); acc.y += __shfl_xor(acc.y, 32);
  acc.z += __shfl_xor(acc.z, 32); acc.w += __shfl_xor(acc.w, 32);

  // Cross-wave reduction via LDS.
  if (lane < 16) {
    sred[wave * L + lq * 4 + 0] = acc.x;
    sred[wave * L + lq * 4 + 1] = acc.y;
    sred[wave * L + lq * 4 + 2] = acc.z;
    sred[wave * L + lq * 4 + 3] = acc.w;
  }
  __syncthreads();
  if (tid < L) {
    const float s = sred[tid] + sred[L + tid] + sred[2 * L + tid] + sred[3 * L + tid];
    partial[(size_t)t * (N * L) + n * L + tid] = s;  // deterministic, no atomics
  }
}

// ---------------------------------------------------------------------------
// Kernel 2: softmax prologue (recomputed per block from the 64 partials,
// 16 KiB L2-hot), then each thread owns exactly ONE output element:
//   out[t,n,c] = dot(q[n,t,c,0:64], probs[n,0:64])
// 16 float4 q loads per thread (L3-resident after K1) + LDS-broadcast probs.
// No cross-lane ops in the main loop; output writes are 1 KiB coalesced.
// ---------------------------------------------------------------------------
__global__ __launch_bounds__(256, 8) void out_kernel(
    const float* __restrict__ q, const float* __restrict__ partial,
    float* __restrict__ out) {
  const int t    = blockIdx.x;
  const int n    = blockIdx.y;
  const int tid  = threadIdx.x;
  const int lane = tid & 63;
  const int wave = tid >> 6;

  __shared__ float sred[4 * L];
  __shared__ __align__(16) float probs[L];

  {
    // Wave w sums partial blocks b in [16w, 16w+16); lane = l index.
    float s = 0.f;
    #pragma unroll 4
    for (int b = wave * 16; b < wave * 16 + 16; ++b)
      s += partial[(size_t)b * (N * L) + n * L + lane];  // coalesced 256 B
    sred[wave * L + lane] = s;
  }
  __syncthreads();
  if (tid < L) {  // wave 0 finishes softmax over l=tid
    float v = sred[tid] + sred[L + tid] + sred[2 * L + tid] + sred[3 * L + tid];
    float m = v;
    #pragma unroll
    for (int off = 32; off > 0; off >>= 1) m = fmaxf(m, __shfl_xor(m, off));
    const float e = __expf(v - m);
    float z = e;
    #pragma unroll
    for (int off = 32; off > 0; off >>= 1) z += __shfl_xor(z, off);
    probs[tid] = e / z;
  }
  __syncthreads();

  // Thread tid == c. 16 independent float4 loads, 256-B lane stride
  // (q row is L3-resident; over-fetched lines consumed by the unroll).
  const float* __restrict__ qrow = q + ((size_t)((n * T + t) * C + tid)) * L;
  float d = 0.f;
  #pragma unroll 8
  for (int lb = 0; lb < 16; ++lb) {
    const float4 qv = *reinterpret_cast<const float4*>(qrow + lb * 4);
    const float4 pv = *reinterpret_cast<const float4*>(&probs[lb * 4]);
    d += qv.x * pv.x + qv.y * pv.y + qv.z * pv.z + qv.w * pv.w;
  }
  out[(size_t)(t * N + n) * C + tid] = d;   // coalesced 1 KiB per block
}

extern "C" void kernel_launch(void* const* d_in, const int* in_sizes, int n_in,
                              void* d_out, int out_size, void* d_ws, size_t ws_size,
                              hipStream_t stream) {
  const float* q = (const float*)d_in[0];   // query: (32,64,256,64) fp32
  const float* k = (const float*)d_in[1];   // key:   (64,32,256)    fp32
  float* out = (float*)d_out;               // out:   (64,32,256)    fp32
  float* partial = (float*)d_ws;            // [64][32][64] fp32 = 512 KiB scratch

  dim3 grid(T, N);                          // 2048 blocks x 256 threads
  scores_partial_kernel<<<grid, 256, 0, stream>>>(q, k, partial);
  out_kernel<<<grid, 256, 0, stream>>>(q, partial, out);
}